// Round 2
// baseline (287.474 us; speedup 1.0000x reference)
//
#include <hip/hip_runtime.h>
#include <hip/hip_cooperative_groups.h>
#include <math.h>

namespace cg = cooperative_groups;

// Problem constants (B=4,S=4096,D=1024,F=4096,E=8,K=2)
#define DD 1024
#define FF 4096
#define NTOK 16384   // B*S

// ws layout (floats):
// [0, 5120)   final sums: k*DD + d, k in {sb,sd,sbb,sdd,sbd}  (atomicAdd-accumulated)
// [5120]      sum(bias)
// Region [0, 5121) is zeroed by hipMemsetAsync before the kernel.

// ---- DPP wave-64 sum: 4 row_ror adds + bcast15 + bcast31, total in lane 63,
//      broadcast to all lanes via readlane. Zero LDS-pipe ops.
template<int CTRL, int RMASK>
__device__ __forceinline__ float dppadd(float v) {
    int m = __builtin_amdgcn_update_dpp(0, __float_as_int(v), CTRL, RMASK, 0xF, false);
    return v + __int_as_float(m);
}
__device__ __forceinline__ float wave_sum64(float v) {
    v = dppadd<0x121, 0xF>(v);   // row_ror:1
    v = dppadd<0x122, 0xF>(v);   // row_ror:2
    v = dppadd<0x124, 0xF>(v);   // row_ror:4
    v = dppadd<0x128, 0xF>(v);   // row_ror:8  -> full row-16 sums
    v = dppadd<0x142, 0xA>(v);   // row_bcast15 into rows 1,3
    v = dppadd<0x143, 0xC>(v);   // row_bcast31 into rows 2,3 -> total in lane 63
    return __int_as_float(__builtin_amdgcn_readlane(__float_as_int(v), 63));
}

__device__ __forceinline__ float sel4(int t, float a, float b, float c, float d) {
    float lo = (t & 1) ? b : a;
    float hi = (t & 1) ? d : c;
    return (t & 2) ? hi : lo;
}

// ============================================================================
// Fused cooperative kernel: phase 1 = W stats (blocks 0..511), grid sync,
// phase 2 = router (all 1024 blocks). 20 KB LDS reused across phases.
// __launch_bounds__(256,4): 4 blocks/CU guaranteed -> 1024 blocks co-resident.
// ============================================================================
__global__ __launch_bounds__(256, 4) void fused_kernel(
    const float* __restrict__ x,
    const float* __restrict__ Wb, const float* __restrict__ Wd,
    const float* __restrict__ bias,
    const float* __restrict__ alpha, const float* __restrict__ beta,
    float* __restrict__ ws, float* __restrict__ out)
{
    __shared__ float4 smem[1280];   // 20 KB, stats-red view then router view

    const int bid  = blockIdx.x;
    const int tid  = threadIdx.x;
    const int lane = tid & 63;
    const int wave = tid >> 6;

    // ---- router it=0 x prefetch, issued before stats so HBM latency overlaps
    const int gw   = bid * 4 + wave;          // global wave id, [0,4096)
    const int tok0 = gw * 4;
    const float4* xr = (const float4*)(x) + (size_t)tok0 * 256;
    float4 xa[4], xb[4];
    #pragma unroll
    for (int t = 0; t < 4; ++t) xa[t] = xr[t * 256 + lane];

    // =========================== phase 1: stats ===========================
    if (bid < 512) {
        const int bx = bid & 3;       // col quarter
        const int by = bid >> 2;      // 32-row group
        const int c4 = bx * 64 + lane;

        const float4* Wb4 = (const float4*)Wb;
        const float4* Wd4 = (const float4*)Wd;

        float4 sb  = make_float4(0.f,0.f,0.f,0.f);
        float4 sd  = sb, sbb = sb, sdd = sb, sbd = sb;

        const int row0 = by * 32 + wave * 8;
        #pragma unroll
        for (int r = 0; r < 8; ++r) {
            const int row = row0 + r;
            float4 b = Wb4[row * 256 + c4];
            float4 d = Wd4[row * 256 + c4];
            sb.x += b.x; sb.y += b.y; sb.z += b.z; sb.w += b.w;
            sd.x += d.x; sd.y += d.y; sd.z += d.z; sd.w += d.w;
            sbb.x += b.x*b.x; sbb.y += b.y*b.y; sbb.z += b.z*b.z; sbb.w += b.w*b.w;
            sdd.x += d.x*d.x; sdd.y += d.y*d.y; sdd.z += d.z*d.z; sdd.w += d.w*d.w;
            sbd.x += b.x*d.x; sbd.y += b.y*d.y; sbd.z += b.z*d.z; sbd.w += b.w*d.w;
        }

        // red[wave][k][lane] view of smem
        smem[(wave * 5 + 0) * 64 + lane] = sb;
        smem[(wave * 5 + 1) * 64 + lane] = sd;
        smem[(wave * 5 + 2) * 64 + lane] = sbb;
        smem[(wave * 5 + 3) * 64 + lane] = sdd;
        smem[(wave * 5 + 4) * 64 + lane] = sbd;
        __syncthreads();

        if (wave == 0) {
            #pragma unroll
            for (int k = 0; k < 5; ++k) {
                float4 acc = smem[k * 64 + lane];
                #pragma unroll
                for (int g = 1; g < 4; ++g) {
                    float4 a = smem[(g * 5 + k) * 64 + lane];
                    acc.x += a.x; acc.y += a.y; acc.z += a.z; acc.w += a.w;
                }
                float* dst = ws + k * DD + c4 * 4;
                atomicAdd(dst + 0, acc.x);
                atomicAdd(dst + 1, acc.y);
                atomicAdd(dst + 2, acc.z);
                atomicAdd(dst + 3, acc.w);
            }
        } else if (wave == 1 && bid == 0) {
            // bias sum: 4096 elems over one wave (64 lanes x 64 elems)
            float s = 0.f;
            #pragma unroll
            for (int i = 0; i < 64; ++i) s += bias[lane + 64 * i];
            s = wave_sum64(s);
            if (lane == 0) ws[5120] = s;
        }
        __threadfence();   // belt-and-braces: publish before grid sync release
    }

    cg::this_grid().sync();

    // =========================== phase 2: router ===========================
    float4* s_mb4 = smem;
    float4* s_md4 = smem + 256;
    float4* s_vb4 = smem + 512;
    float4* s_vd4 = smem + 768;
    float4* s_cb4 = smem + 1024;
    float* s_mb = (float*)s_mb4;
    float* s_md = (float*)s_md4;
    float* s_vb = (float*)s_vb4;
    float* s_vd = (float*)s_vd4;
    float* s_cb = (float*)s_cb4;

    const float invF = 1.0f / (float)FF;
    const float* fin = ws;

    for (int i = tid; i < DD; i += 256) {
        float sb  = fin[i];
        float sd  = fin[DD + i];
        float sbb = fin[2 * DD + i];
        float sdd = fin[3 * DD + i];
        float sbd = fin[4 * DD + i];
        float mb = sb * invF, md = sd * invF;
        s_mb[i] = mb;
        s_md[i] = md;
        s_vb[i] = fmaxf(sbb * invF - mb * mb, 0.f);
        s_vd[i] = fmaxf(sdd * invF - md * md, 0.f);
        s_cb[i] = sbd * invF - mb * md;
    }
    const float bias_mean = fin[5120] * invF;
    __syncthreads();

    float s1[4], s2[4], t1[4], t2[4], t3[4];
    #pragma unroll
    for (int t = 0; t < 4; ++t) { s1[t]=0.f; s2[t]=0.f; t1[t]=0.f; t2[t]=0.f; t3[t]=0.f; }

    #pragma unroll
    for (int it = 0; it < 4; ++it) {
        const int i4 = it * 64 + lane;
        // software pipeline: issue next iteration's loads before consuming this one
        if (it < 3) {
            #pragma unroll
            for (int t = 0; t < 4; ++t) xb[t] = xr[t * 256 + (it + 1) * 64 + lane];
        }
        const float4 mb = s_mb4[i4];
        const float4 md = s_md4[i4];
        const float4 vb = s_vb4[i4];
        const float4 vd = s_vd4[i4];
        const float4 cb = s_cb4[i4];
        #pragma unroll
        for (int t = 0; t < 4; ++t) {
            float4 xv = xa[t];
            float x2x = xv.x*xv.x, x2y = xv.y*xv.y, x2z = xv.z*xv.z, x2w = xv.w*xv.w;
            s1[t] += xv.x*mb.x + xv.y*mb.y + xv.z*mb.z + xv.w*mb.w;
            s2[t] += xv.x*md.x + xv.y*md.y + xv.z*md.z + xv.w*md.w;
            t1[t] += x2x*vb.x + x2y*vb.y + x2z*vb.z + x2w*vb.w;
            t2[t] += x2x*vd.x + x2y*vd.y + x2z*vd.z + x2w*vd.w;
            t3[t] += x2x*cb.x + x2y*cb.y + x2z*cb.z + x2w*cb.w;
        }
        #pragma unroll
        for (int t = 0; t < 4; ++t) xa[t] = xb[t];
    }

    // ---- DPP wave reductions: 20 wave-uniform sums
    float A1[4], A2[4], B1[4], B2[4], B3[4];
    #pragma unroll
    for (int t = 0; t < 4; ++t) {
        A1[t] = wave_sum64(s1[t]);
        A2[t] = wave_sum64(s2[t]);
        B1[t] = wave_sum64(t1[t]);
        B2[t] = wave_sum64(t2[t]);
        B3[t] = wave_sum64(t3[t]);
    }

    // ---- lanes 0..31: token tt = lane>>3, expert e = lane&7
    const int tt = (lane >> 3) & 3;
    const int e  = lane & 7;
    const float a_e = alpha[e];
    const float b_e = beta[e];

    float S1 = sel4(tt, A1[0], A1[1], A1[2], A1[3]);
    float S2 = sel4(tt, A2[0], A2[1], A2[2], A2[3]);
    float T1 = sel4(tt, B1[0], B1[1], B1[2], B1[3]);
    float T2 = sel4(tt, B2[0], B2[1], B2[2], B2[3]);
    float T3 = sel4(tt, B3[0], B3[1], B3[2], B3[3]);

    float mu  = a_e * S1 + b_e * S2 + bias_mean;
    float var = a_e * a_e * T1 + b_e * b_e * T2 + 2.f * a_e * b_e * T3;
    float z   = mu / sqrtf(2.f * (var + 1e-8f));
    float logit = erff(z);

    // gather the 8 expert logits of this lane's token
    const int base = lane & 56;
    float l[8];
    #pragma unroll
    for (int q = 0; q < 8; ++q) l[q] = __shfl(logit, base + q);

    // top-2, tie-break = first index (matches lax.top_k)
    float vmax = l[0]; int i0 = 0;
    #pragma unroll
    for (int q = 1; q < 8; ++q) { if (l[q] > vmax) { vmax = l[q]; i0 = q; } }
    float vsec = -1e30f; int i1 = 0;
    #pragma unroll
    for (int q = 0; q < 8; ++q) { if (q != i0 && l[q] > vsec) { vsec = l[q]; i1 = q; } }

    float e1  = __expf(vsec - vmax);
    float inv = 1.f / (1.f + e1);
    float wtop = inv, wsec = e1 * inv;

    if (lane < 32) {
        const int token = tok0 + tt;
        float w = (e == i0) ? wtop : ((e == i1) ? wsec : 0.f);
        out[(size_t)token * 8 + e] = w;
        out[(size_t)NTOK * 8 + (size_t)token * 8 + e] = logit;
    }
}

// ============================================================================
// Fallback path (identical math, 2 dispatches) in case cooperative launch
// is rejected at runtime.
// ============================================================================
__global__ __launch_bounds__(256) void stats1_kernel(
    const float* __restrict__ Wb, const float* __restrict__ Wd,
    const float* __restrict__ bias, float* __restrict__ ws)
{
    const int tx = threadIdx.x;
    const int ty = threadIdx.y;
    const int bx = blockIdx.x;
    const int by = blockIdx.y;
    const int c4 = bx * 64 + tx;

    const float4* Wb4 = (const float4*)Wb;
    const float4* Wd4 = (const float4*)Wd;

    float4 sb  = make_float4(0.f,0.f,0.f,0.f);
    float4 sd  = sb, sbb = sb, sdd = sb, sbd = sb;

    const int row0 = by * 32 + ty * 8;
    #pragma unroll
    for (int r = 0; r < 8; ++r) {
        const int row = row0 + r;
        float4 b = Wb4[row * 256 + c4];
        float4 d = Wd4[row * 256 + c4];
        sb.x += b.x; sb.y += b.y; sb.z += b.z; sb.w += b.w;
        sd.x += d.x; sd.y += d.y; sd.z += d.z; sd.w += d.w;
        sbb.x += b.x*b.x; sbb.y += b.y*b.y; sbb.z += b.z*b.z; sbb.w += b.w*b.w;
        sdd.x += d.x*d.x; sdd.y += d.y*d.y; sdd.z += d.z*d.z; sdd.w += d.w*d.w;
        sbd.x += b.x*d.x; sbd.y += b.y*d.y; sbd.z += b.z*d.z; sbd.w += b.w*d.w;
    }

    __shared__ float4 red[4][5][64];
    red[ty][0][tx] = sb;
    red[ty][1][tx] = sd;
    red[ty][2][tx] = sbb;
    red[ty][3][tx] = sdd;
    red[ty][4][tx] = sbd;
    __syncthreads();

    if (ty == 0) {
        #pragma unroll
        for (int k = 0; k < 5; ++k) {
            float4 acc = red[0][k][tx];
            #pragma unroll
            for (int g = 1; g < 4; ++g) {
                float4 a = red[g][k][tx];
                acc.x += a.x; acc.y += a.y; acc.z += a.z; acc.w += a.w;
            }
            float* dst = ws + k * DD + c4 * 4;
            atomicAdd(dst + 0, acc.x);
            atomicAdd(dst + 1, acc.y);
            atomicAdd(dst + 2, acc.z);
            atomicAdd(dst + 3, acc.w);
        }
    } else if (ty == 1 && bx == 0 && by == 0) {
        float s = 0.f;
        #pragma unroll
        for (int i = 0; i < 64; ++i) s += bias[tx + 64 * i];
        s = wave_sum64(s);
        if (tx == 0) ws[5120] = s;
    }
}

__global__ __launch_bounds__(256) void router_kernel(
    const float* __restrict__ x,
    const float* __restrict__ alpha, const float* __restrict__ beta,
    const float* __restrict__ ws, float* __restrict__ out)
{
    __shared__ float4 s_mb4[256], s_md4[256], s_vb4[256], s_vd4[256], s_cb4[256];
    float* s_mb = (float*)s_mb4;
    float* s_md = (float*)s_md4;
    float* s_vb = (float*)s_vb4;
    float* s_vd = (float*)s_vd4;
    float* s_cb = (float*)s_cb4;

    const int tid  = threadIdx.x;
    const int lane = tid & 63;
    const int wave = tid >> 6;
    const int gw   = blockIdx.x * 4 + wave;
    const int tok0 = gw * 4;

    const float4* xr = (const float4*)(x) + (size_t)tok0 * 256;

    const float invF = 1.0f / (float)FF;
    const float* fin = ws;

    float4 xa[4], xb[4];
    #pragma unroll
    for (int t = 0; t < 4; ++t) xa[t] = xr[t * 256 + lane];

    for (int i = tid; i < DD; i += 256) {
        float sb  = fin[i];
        float sd  = fin[DD + i];
        float sbb = fin[2 * DD + i];
        float sdd = fin[3 * DD + i];
        float sbd = fin[4 * DD + i];
        float mb = sb * invF, md = sd * invF;
        s_mb[i] = mb;
        s_md[i] = md;
        s_vb[i] = fmaxf(sbb * invF - mb * mb, 0.f);
        s_vd[i] = fmaxf(sdd * invF - md * md, 0.f);
        s_cb[i] = sbd * invF - mb * md;
    }
    const float bias_mean = fin[5120] * invF;
    __syncthreads();

    float s1[4], s2[4], t1[4], t2[4], t3[4];
    #pragma unroll
    for (int t = 0; t < 4; ++t) { s1[t]=0.f; s2[t]=0.f; t1[t]=0.f; t2[t]=0.f; t3[t]=0.f; }

    #pragma unroll
    for (int it = 0; it < 4; ++it) {
        const int i4 = it * 64 + lane;
        if (it < 3) {
            #pragma unroll
            for (int t = 0; t < 4; ++t) xb[t] = xr[t * 256 + (it + 1) * 64 + lane];
        }
        const float4 mb = s_mb4[i4];
        const float4 md = s_md4[i4];
        const float4 vb = s_vb4[i4];
        const float4 vd = s_vd4[i4];
        const float4 cb = s_cb4[i4];
        #pragma unroll
        for (int t = 0; t < 4; ++t) {
            float4 xv = xa[t];
            float x2x = xv.x*xv.x, x2y = xv.y*xv.y, x2z = xv.z*xv.z, x2w = xv.w*xv.w;
            s1[t] += xv.x*mb.x + xv.y*mb.y + xv.z*mb.z + xv.w*mb.w;
            s2[t] += xv.x*md.x + xv.y*md.y + xv.z*md.z + xv.w*md.w;
            t1[t] += x2x*vb.x + x2y*vb.y + x2z*vb.z + x2w*vb.w;
            t2[t] += x2x*vd.x + x2y*vd.y + x2z*vd.z + x2w*vd.w;
            t3[t] += x2x*cb.x + x2y*cb.y + x2z*cb.z + x2w*cb.w;
        }
        #pragma unroll
        for (int t = 0; t < 4; ++t) xa[t] = xb[t];
    }

    float A1[4], A2[4], B1[4], B2[4], B3[4];
    #pragma unroll
    for (int t = 0; t < 4; ++t) {
        A1[t] = wave_sum64(s1[t]);
        A2[t] = wave_sum64(s2[t]);
        B1[t] = wave_sum64(t1[t]);
        B2[t] = wave_sum64(t2[t]);
        B3[t] = wave_sum64(t3[t]);
    }

    const int tt = (lane >> 3) & 3;
    const int e  = lane & 7;
    const float a_e = alpha[e];
    const float b_e = beta[e];

    float S1 = sel4(tt, A1[0], A1[1], A1[2], A1[3]);
    float S2 = sel4(tt, A2[0], A2[1], A2[2], A2[3]);
    float T1 = sel4(tt, B1[0], B1[1], B1[2], B1[3]);
    float T2 = sel4(tt, B2[0], B2[1], B2[2], B2[3]);
    float T3 = sel4(tt, B3[0], B3[1], B3[2], B3[3]);

    float mu  = a_e * S1 + b_e * S2 + bias_mean;
    float var = a_e * a_e * T1 + b_e * b_e * T2 + 2.f * a_e * b_e * T3;
    float z   = mu / sqrtf(2.f * (var + 1e-8f));
    float logit = erff(z);

    const int base = lane & 56;
    float l[8];
    #pragma unroll
    for (int q = 0; q < 8; ++q) l[q] = __shfl(logit, base + q);

    float vmax = l[0]; int i0 = 0;
    #pragma unroll
    for (int q = 1; q < 8; ++q) { if (l[q] > vmax) { vmax = l[q]; i0 = q; } }
    float vsec = -1e30f; int i1 = 0;
    #pragma unroll
    for (int q = 0; q < 8; ++q) { if (q != i0 && l[q] > vsec) { vsec = l[q]; i1 = q; } }

    float e1  = __expf(vsec - vmax);
    float inv = 1.f / (1.f + e1);
    float wtop = inv, wsec = e1 * inv;

    if (lane < 32) {
        const int token = tok0 + tt;
        float w = (e == i0) ? wtop : ((e == i1) ? wsec : 0.f);
        out[(size_t)token * 8 + e] = w;
        out[(size_t)NTOK * 8 + (size_t)token * 8 + e] = logit;
    }
}

extern "C" void kernel_launch(void* const* d_in, const int* in_sizes, int n_in,
                              void* d_out, int out_size, void* d_ws, size_t ws_size,
                              hipStream_t stream)
{
    const float* x     = (const float*)d_in[0];
    const float* Wb    = (const float*)d_in[1];
    const float* Wd    = (const float*)d_in[2];
    const float* bias  = (const float*)d_in[3];
    const float* alpha = (const float*)d_in[4];
    const float* beta  = (const float*)d_in[5];
    float* out = (float*)d_out;
    float* ws  = (float*)d_ws;

    // zero the atomic accumulation region (5*1024 sums + bias slot)
    hipMemsetAsync(ws, 0, (5 * DD + 1) * sizeof(float), stream);

    void* args[] = { (void*)&x, (void*)&Wb, (void*)&Wd, (void*)&bias,
                     (void*)&alpha, (void*)&beta, (void*)&ws, (void*)&out };
    hipError_t err = hipLaunchCooperativeKernel((const void*)fused_kernel,
                                                dim3(1024), dim3(256),
                                                args, 0, stream);
    if (err != hipSuccess) {
        // fallback: verified 2-dispatch path
        dim3 b1(64, 4), g1(4, 128);
        stats1_kernel<<<g1, b1, 0, stream>>>(Wb, Wd, bias, ws);
        router_kernel<<<1024, 256, 0, stream>>>(x, alpha, beta, ws, out);
    }
}

// Round 3
// 146.567 us; speedup vs baseline: 1.9614x; 1.9614x over previous
//
#include <hip/hip_runtime.h>
#include <math.h>

// Problem constants (B=4,S=4096,D=1024,F=4096,E=8,K=2)
#define DD 1024
#define FF 4096
#define NTOK 16384   // B*S

// ws layout (floats):
// [0, 5120)   final sums: k*DD + d, k in {sb,sd,sbb,sdd,sbd}  (atomicAdd-accumulated)
// [5120]      sum(bias)
// Region [0, 5121) is zeroed by hipMemsetAsync before stats1.

// ---- DPP wave-64 sum: 4 row_ror adds + bcast15 + bcast31, total in lane 63,
//      broadcast to all lanes via readlane. Zero LDS-pipe ops.
template<int CTRL, int RMASK>
__device__ __forceinline__ float dppadd(float v) {
    int m = __builtin_amdgcn_update_dpp(0, __float_as_int(v), CTRL, RMASK, 0xF, false);
    return v + __int_as_float(m);
}
__device__ __forceinline__ float wave_sum64(float v) {
    v = dppadd<0x121, 0xF>(v);   // row_ror:1
    v = dppadd<0x122, 0xF>(v);   // row_ror:2
    v = dppadd<0x124, 0xF>(v);   // row_ror:4
    v = dppadd<0x128, 0xF>(v);   // row_ror:8  -> full row-16 sums
    v = dppadd<0x142, 0xA>(v);   // row_bcast15 into rows 1,3
    v = dppadd<0x143, 0xC>(v);   // row_bcast31 into rows 2,3 -> total in lane 63
    return __int_as_float(__builtin_amdgcn_readlane(__float_as_int(v), 63));
}

__device__ __forceinline__ float sel4(int t, float a, float b, float c, float d) {
    float lo = (t & 1) ? b : a;
    float hi = (t & 1) ? d : c;
    return (t & 2) ? hi : lo;
}

// ============================================================================
// stats1: per-32-row-group W stats, cross-wave LDS reduce, atomicAdd into the
// global finals. No threadfence (kernel-boundary release publishes for k2).
// ============================================================================
__global__ __launch_bounds__(256) void stats1_kernel(
    const float* __restrict__ Wb, const float* __restrict__ Wd,
    const float* __restrict__ bias, float* __restrict__ ws)
{
    const int tx = threadIdx.x;   // 0..63 : float4 column
    const int ty = threadIdx.y;   // 0..3  : row subgroup (one wave each)
    const int bx = blockIdx.x;    // 0..3  : col quarter
    const int by = blockIdx.y;    // 0..127: 32-row group
    const int c4 = bx * 64 + tx;  // float4 column index in [0,256)

    const float4* Wb4 = (const float4*)Wb;
    const float4* Wd4 = (const float4*)Wd;

    float4 sb  = make_float4(0.f,0.f,0.f,0.f);
    float4 sd  = sb, sbb = sb, sdd = sb, sbd = sb;

    const int row0 = by * 32 + ty * 8;
    #pragma unroll
    for (int r = 0; r < 8; ++r) {
        const int row = row0 + r;
        float4 b = Wb4[row * 256 + c4];
        float4 d = Wd4[row * 256 + c4];
        sb.x += b.x; sb.y += b.y; sb.z += b.z; sb.w += b.w;
        sd.x += d.x; sd.y += d.y; sd.z += d.z; sd.w += d.w;
        sbb.x += b.x*b.x; sbb.y += b.y*b.y; sbb.z += b.z*b.z; sbb.w += b.w*b.w;
        sdd.x += d.x*d.x; sdd.y += d.y*d.y; sdd.z += d.z*d.z; sdd.w += d.w*d.w;
        sbd.x += b.x*d.x; sbd.y += b.y*d.y; sbd.z += b.z*d.z; sbd.w += b.w*d.w;
    }

    __shared__ float4 red[4][5][64];   // 20 KB

    red[ty][0][tx] = sb;
    red[ty][1][tx] = sd;
    red[ty][2][tx] = sbb;
    red[ty][3][tx] = sdd;
    red[ty][4][tx] = sbd;
    __syncthreads();

    if (ty == 0) {
        // cross-wave reduce then fold this block's partial into the global
        // finals (128 adders per address -> negligible contention)
        #pragma unroll
        for (int k = 0; k < 5; ++k) {
            float4 acc = red[0][k][tx];
            #pragma unroll
            for (int g = 1; g < 4; ++g) {
                float4 a = red[g][k][tx];
                acc.x += a.x; acc.y += a.y; acc.z += a.z; acc.w += a.w;
            }
            float* dst = ws + k * DD + c4 * 4;
            atomicAdd(dst + 0, acc.x);
            atomicAdd(dst + 1, acc.y);
            atomicAdd(dst + 2, acc.z);
            atomicAdd(dst + 3, acc.w);
        }
    } else if (ty == 1 && bx == 0 && by == 0) {
        // bias sum: 4096 elems over one wave (64 lanes x 64 elems), DPP reduce
        float s = 0.f;
        #pragma unroll
        for (int i = 0; i < 64; ++i) s += bias[tx + 64 * i];
        s = wave_sum64(s);
        if (tx == 0) ws[5120] = s;
    }
}

// ============================================================================
// router: one wave = 4 tokens. ALL 16 x-float4 loads issued up front; the
// ws->LDS staging (loads issued after x, so its waitcnt drains x too) plus
// the barrier hide the entire global latency; the FMA loop then runs
// stall-free out of registers + LDS.
// ============================================================================
__global__ __launch_bounds__(256, 4) void router_kernel(
    const float* __restrict__ x,
    const float* __restrict__ alpha, const float* __restrict__ beta,
    const float* __restrict__ ws, float* __restrict__ out)
{
    __shared__ float4 smem[1280];   // 20 KB
    float4* s_mb4 = smem;
    float4* s_md4 = smem + 256;
    float4* s_vb4 = smem + 512;
    float4* s_vd4 = smem + 768;
    float4* s_cb4 = smem + 1024;
    float* s_mb = (float*)s_mb4;
    float* s_md = (float*)s_md4;
    float* s_vb = (float*)s_vb4;
    float* s_vd = (float*)s_vd4;
    float* s_cb = (float*)s_cb4;

    const int tid  = threadIdx.x;
    const int lane = tid & 63;
    const int wave = tid >> 6;
    const int gw   = blockIdx.x * 4 + wave;   // global wave id, [0,4096)
    const int tok0 = gw * 4;

    const float4* xr = (const float4*)(x) + (size_t)tok0 * 256;

    // ---- issue ALL 16 x loads up front, in consumption order (it-major)
    float4 xv[16];
    #pragma unroll
    for (int it = 0; it < 4; ++it) {
        #pragma unroll
        for (int t = 0; t < 4; ++t)
            xv[it * 4 + t] = xr[t * 256 + it * 64 + lane];
    }

    const float invF = 1.0f / (float)FF;
    const float* fin = ws;

    for (int i = tid; i < DD; i += 256) {
        float sb  = fin[i];
        float sd  = fin[DD + i];
        float sbb = fin[2 * DD + i];
        float sdd = fin[3 * DD + i];
        float sbd = fin[4 * DD + i];
        float mb = sb * invF, md = sd * invF;
        s_mb[i] = mb;
        s_md[i] = md;
        s_vb[i] = fmaxf(sbb * invF - mb * mb, 0.f);
        s_vd[i] = fmaxf(sdd * invF - md * md, 0.f);
        s_cb[i] = sbd * invF - mb * md;
    }
    const float bias_mean = fin[5120] * invF;
    __syncthreads();

    float s1[4], s2[4], t1[4], t2[4], t3[4];
    #pragma unroll
    for (int t = 0; t < 4; ++t) { s1[t]=0.f; s2[t]=0.f; t1[t]=0.f; t2[t]=0.f; t3[t]=0.f; }

    #pragma unroll
    for (int it = 0; it < 4; ++it) {
        const int i4 = it * 64 + lane;
        const float4 mb = s_mb4[i4];
        const float4 md = s_md4[i4];
        const float4 vb = s_vb4[i4];
        const float4 vd = s_vd4[i4];
        const float4 cb = s_cb4[i4];
        #pragma unroll
        for (int t = 0; t < 4; ++t) {
            float4 xvv = xv[it * 4 + t];
            float x2x = xvv.x*xvv.x, x2y = xvv.y*xvv.y, x2z = xvv.z*xvv.z, x2w = xvv.w*xvv.w;
            s1[t] += xvv.x*mb.x + xvv.y*mb.y + xvv.z*mb.z + xvv.w*mb.w;
            s2[t] += xvv.x*md.x + xvv.y*md.y + xvv.z*md.z + xvv.w*md.w;
            t1[t] += x2x*vb.x + x2y*vb.y + x2z*vb.z + x2w*vb.w;
            t2[t] += x2x*vd.x + x2y*vd.y + x2z*vd.z + x2w*vd.w;
            t3[t] += x2x*cb.x + x2y*cb.y + x2z*cb.z + x2w*cb.w;
        }
    }

    // ---- DPP wave reductions: 20 wave-uniform sums (no LDS-pipe traffic)
    float A1[4], A2[4], B1[4], B2[4], B3[4];
    #pragma unroll
    for (int t = 0; t < 4; ++t) {
        A1[t] = wave_sum64(s1[t]);
        A2[t] = wave_sum64(s2[t]);
        B1[t] = wave_sum64(t1[t]);
        B2[t] = wave_sum64(t2[t]);
        B3[t] = wave_sum64(t3[t]);
    }

    // ---- lanes 0..31: token tt = lane>>3, expert e = lane&7
    const int tt = (lane >> 3) & 3;
    const int e  = lane & 7;
    const float a_e = alpha[e];
    const float b_e = beta[e];

    float S1 = sel4(tt, A1[0], A1[1], A1[2], A1[3]);
    float S2 = sel4(tt, A2[0], A2[1], A2[2], A2[3]);
    float T1 = sel4(tt, B1[0], B1[1], B1[2], B1[3]);
    float T2 = sel4(tt, B2[0], B2[1], B2[2], B2[3]);
    float T3 = sel4(tt, B3[0], B3[1], B3[2], B3[3]);

    float mu  = a_e * S1 + b_e * S2 + bias_mean;
    float var = a_e * a_e * T1 + b_e * b_e * T2 + 2.f * a_e * b_e * T3;
    float z   = mu / sqrtf(2.f * (var + 1e-8f));
    float logit = erff(z);

    // gather the 8 expert logits of this lane's token
    const int base = lane & 56;   // start of this token's 8-lane group
    float l[8];
    #pragma unroll
    for (int q = 0; q < 8; ++q) l[q] = __shfl(logit, base + q);

    // top-2, tie-break = first index (matches lax.top_k)
    float vmax = l[0]; int i0 = 0;
    #pragma unroll
    for (int q = 1; q < 8; ++q) { if (l[q] > vmax) { vmax = l[q]; i0 = q; } }
    float vsec = -1e30f; int i1 = 0;
    #pragma unroll
    for (int q = 0; q < 8; ++q) { if (q != i0 && l[q] > vsec) { vsec = l[q]; i1 = q; } }

    float e1  = __expf(vsec - vmax);
    float inv = 1.f / (1.f + e1);
    float wtop = inv, wsec = e1 * inv;

    if (lane < 32) {
        const int token = tok0 + tt;
        float w = (e == i0) ? wtop : ((e == i1) ? wsec : 0.f);
        out[(size_t)token * 8 + e] = w;
        out[(size_t)NTOK * 8 + (size_t)token * 8 + e] = logit;
    }
}

extern "C" void kernel_launch(void* const* d_in, const int* in_sizes, int n_in,
                              void* d_out, int out_size, void* d_ws, size_t ws_size,
                              hipStream_t stream)
{
    const float* x     = (const float*)d_in[0];
    const float* Wb    = (const float*)d_in[1];
    const float* Wd    = (const float*)d_in[2];
    const float* bias  = (const float*)d_in[3];
    const float* alpha = (const float*)d_in[4];
    const float* beta  = (const float*)d_in[5];
    float* out = (float*)d_out;
    float* ws  = (float*)d_ws;

    // zero the atomic accumulation region (5*1024 sums + bias slot)
    hipMemsetAsync(ws, 0, (5 * DD + 1) * sizeof(float), stream);

    dim3 b1(64, 4), g1(4, 128);
    stats1_kernel<<<g1, b1, 0, stream>>>(Wb, Wd, bias, ws);

    router_kernel<<<1024, 256, 0, stream>>>(x, alpha, beta, ws, out);
}